// Round 1
// baseline (519.577 us; speedup 1.0000x reference)
//
#include <hip/hip_runtime.h>
#include <hip/hip_bf16.h>

// Problem constants (from reference)
#define NUSERS   10000
#define NITEMS   100000
#define DIM      64
#define BATCH    4096

// GEMM tiling
#define KPAD     10240          // 320 * 32, zero-padded K -> every chunk uniform
#define NSTEPS   320            // K-steps of 32
#define STEPS_PER_CHUNK 16
#define NCHUNK   20             // 320 / 16, all full
#define MT       64             // batch rows per block

typedef __bf16 bf16_t;
typedef __bf16 bf16x8 __attribute__((ext_vector_type(8)));
typedef float  f32x4  __attribute__((ext_vector_type(4)));

// ---------------------------------------------------------------------------
// Kernel 1: coalesced LDS-tiled transpose + convert
//   user_emb[k][d] (f32) -> ueT[d][k] (bf16), k zero-padded to KPAD.
// 64x64 tile per block; both global read and global write fully coalesced.
// ---------------------------------------------------------------------------
__global__ __launch_bounds__(256) void prep_ueT_kernel(
        const float* __restrict__ user_emb, bf16_t* __restrict__ ueT) {
    __shared__ float tile[64][65];          // +1 pad: conflict-free transpose
    const int t  = threadIdx.x;
    const int k0 = blockIdx.x * 64;
    const int x  = t & 63;
    const int r  = t >> 6;                  // 0..3
    #pragma unroll
    for (int i = 0; i < 16; ++i) {
        const int kl = i * 4 + r;
        const int k  = k0 + kl;
        tile[kl][x] = (k < NUSERS) ? user_emb[(size_t)k * DIM + x] : 0.0f;
    }
    __syncthreads();
    #pragma unroll
    for (int i = 0; i < 16; ++i) {
        const int dl = i * 4 + r;
        // write ueT[dl][k0 + x], x = coalesced k within the tile
        ueT[(size_t)dl * KPAD + k0 + x] = (bf16_t)tile[x][dl];
    }
}

// ---------------------------------------------------------------------------
// Kernel 2: out[b] = dot(user_emb[users[b]], item_emb[items[b]])
// Plain store — initializes d_out (poisoned by harness) before atomics.
// One wave per batch element.
// ---------------------------------------------------------------------------
__global__ void pos_kernel(const float* __restrict__ user_emb,
                           const float* __restrict__ item_emb,
                           const int* __restrict__ users,
                           const int* __restrict__ items,
                           float* __restrict__ out) {
    int w    = threadIdx.x >> 6;
    int lane = threadIdx.x & 63;
    int b    = blockIdx.x * 4 + w;
    if (b >= BATCH) return;
    int uid = users[b];
    int iid = items[b];
    float v = user_emb[(size_t)uid * DIM + lane] * item_emb[(size_t)iid * DIM + lane];
    v += __shfl_xor(v, 32, 64);
    v += __shfl_xor(v, 16, 64);
    v += __shfl_xor(v, 8, 64);
    v += __shfl_xor(v, 4, 64);
    v += __shfl_xor(v, 2, 64);
    v += __shfl_xor(v, 1, 64);
    if (lane == 0) out[b] = v;
}

// ---------------------------------------------------------------------------
// Kernel 3: social term — barrier-free, LDS-free MFMA streaming GEMM.
//   V[m, d] = sum_k sw[users[m], k] * user_emb[k, d]
//   out[m] += sum_d V[m, d] * item_emb[items[m], d]
//
// Key structural facts:
//  * A (sw rows) has ZERO cross-lane reuse -> no point staging in LDS. The
//    16x16x32 A-fragment for lane (c = lane&15, q = lane>>4) is
//    A[m=c][k=8q..8q+8]: 8 k-contiguous floats -> two float4 loads straight
//    from global, converted to bf16 in registers.
//  * B-fragment is B[k=8q..][n=c+16t] = 16 contiguous bytes of ueT[n][k]
//    -> direct bf16x8 global load. ueT is 1.3 MB, L2/L3-resident.
//  * Inner loop therefore has NO __syncthreads and NO vmcnt(0) chokepoints;
//    the compiler software-pipelines loads across steps. MLP per lane:
//    6 x 16 B per step x unroll depth, vs 2 x 16 B per barrier before.
//
// Grid: x = K-chunk (20, uniform 16 steps thanks to KPAD), y = M-tile (64).
// Block 256 = 4 waves; wave w owns rows [16w, 16w+16) x all 64 cols via
// four 16x16x32 MFMA accumulators.
// ---------------------------------------------------------------------------
__global__ __launch_bounds__(256, 4) void social_kernel(
        const float* __restrict__ sw,
        const bf16_t* __restrict__ ueT,
        const float* __restrict__ item_emb,
        const int* __restrict__ users,
        const int* __restrict__ items,
        float* __restrict__ out) {
    const int tid  = threadIdx.x;
    const int lane = tid & 63;
    const int w    = tid >> 6;       // wave id: rows [16w, 16w+16)
    const int c    = lane & 15;      // A row within wave tile / B col within n-frag
    const int q    = lane >> 4;      // k sub-offset group 0..3

    const int m0    = blockIdx.y * MT;
    const int myrow = m0 + 16 * w + c;
    const size_t a_base = (size_t)users[myrow] * NUSERS;   // this lane's sw row

    // Per-lane B row bases (ueT[d][k], d = c + 16t)
    const bf16_t* b0p = ueT + (size_t)(c     ) * KPAD;
    const bf16_t* b1p = ueT + (size_t)(c + 16) * KPAD;
    const bf16_t* b2p = ueT + (size_t)(c + 32) * KPAD;
    const bf16_t* b3p = ueT + (size_t)(c + 48) * KPAD;

    f32x4 acc0 = {0.f, 0.f, 0.f, 0.f};
    f32x4 acc1 = {0.f, 0.f, 0.f, 0.f};
    f32x4 acc2 = {0.f, 0.f, 0.f, 0.f};
    f32x4 acc3 = {0.f, 0.f, 0.f, 0.f};

    const int kbase = blockIdx.x * (STEPS_PER_CHUNK * 32) + 8 * q;

    #pragma unroll 2
    for (int s = 0; s < STEPS_PER_CHUNK; ++s) {
        const int ka = kbase + 32 * s;     // k offset of this lane's 8-group

        // A: 8 f32 from this lane's sw row (zero beyond real K; NUSERS%8==0)
        float4 a0 = {0.f, 0.f, 0.f, 0.f};
        float4 a1 = {0.f, 0.f, 0.f, 0.f};
        if (ka < NUSERS) {
            const float4* p = (const float4*)(sw + a_base + ka);
            a0 = p[0];
            a1 = p[1];
        }

        // B: four bf16x8 fragments straight from L2-resident ueT
        const bf16x8 b0 = *(const bf16x8*)(b0p + ka);
        const bf16x8 b1 = *(const bf16x8*)(b1p + ka);
        const bf16x8 b2 = *(const bf16x8*)(b2p + ka);
        const bf16x8 b3 = *(const bf16x8*)(b3p + ka);

        bf16x8 av;
        av[0] = (bf16_t)a0.x; av[1] = (bf16_t)a0.y;
        av[2] = (bf16_t)a0.z; av[3] = (bf16_t)a0.w;
        av[4] = (bf16_t)a1.x; av[5] = (bf16_t)a1.y;
        av[6] = (bf16_t)a1.z; av[7] = (bf16_t)a1.w;

        acc0 = __builtin_amdgcn_mfma_f32_16x16x32_bf16(av, b0, acc0, 0, 0, 0);
        acc1 = __builtin_amdgcn_mfma_f32_16x16x32_bf16(av, b1, acc1, 0, 0, 0);
        acc2 = __builtin_amdgcn_mfma_f32_16x16x32_bf16(av, b2, acc2, 0, 0, 0);
        acc3 = __builtin_amdgcn_mfma_f32_16x16x32_bf16(av, b3, acc3, 0, 0, 0);
    }

    // Epilogue: C/D layout (verified m89): col = lane&15, row = (lane>>4)*4 + r.
    // Row (local) = 16w + 4q + r; col of acc_t element = 16t + c.
    // out_partial[row] = sum_d C[row][d] * item_emb[items[row]][d]
    #pragma unroll
    for (int r = 0; r < 4; ++r) {
        const int grow = m0 + 16 * w + 4 * q + r;
        const int iid  = items[grow];          // uniform across the 16-lane group
        const float* ie = item_emb + (size_t)iid * DIM;
        float v = acc0[r] * ie[c]
                + acc1[r] * ie[c + 16]
                + acc2[r] * ie[c + 32]
                + acc3[r] * ie[c + 48];
        // reduce across the 16 lanes (c = 0..15) holding this row
        v += __shfl_xor(v, 1, 64);
        v += __shfl_xor(v, 2, 64);
        v += __shfl_xor(v, 4, 64);
        v += __shfl_xor(v, 8, 64);
        if (c == 0) atomicAdd(out + grow, v);
    }
}

// ---------------------------------------------------------------------------
extern "C" void kernel_launch(void* const* d_in, const int* in_sizes, int n_in,
                              void* d_out, int out_size, void* d_ws, size_t ws_size,
                              hipStream_t stream) {
    const float* user_emb = (const float*)d_in[0];
    const float* item_emb = (const float*)d_in[1];
    const float* sw       = (const float*)d_in[2];
    const int*   users    = (const int*)d_in[3];
    const int*   items    = (const int*)d_in[4];
    float* out = (float*)d_out;

    bf16_t* ueT = (bf16_t*)d_ws;   // DIM * KPAD bf16 = 1.31 MB

    // 1) transpose+convert user_emb (runs every call; ws is re-poisoned)
    prep_ueT_kernel<<<KPAD / 64, 256, 0, stream>>>(user_emb, ueT);

    // 2) positive dot, initializes out (stream-ordered before social atomics)
    pos_kernel<<<BATCH / 4, 256, 0, stream>>>(user_emb, item_emb, users, items, out);

    // 3) social GEMM + fused epilogue dot, atomic accumulate into out
    social_kernel<<<dim3(NCHUNK, BATCH / MT), 256, 0, stream>>>(
        sw, ueT, item_emb, users, items, out);
}

// Round 2
// 518.153 us; speedup vs baseline: 1.0027x; 1.0027x over previous
//
#include <hip/hip_runtime.h>
#include <hip/hip_bf16.h>

// Problem constants (from reference)
#define NUSERS   10000
#define NITEMS   100000
#define DIM      64
#define BATCH    4096

// GEMM tiling
#define KPAD     10240          // 320 * 32, zero-padded K -> every chunk uniform
#define NSTEPS   320            // K-steps of 32
#define STEPS_PER_CHUNK 16
#define NCHUNK   20             // 320 / 16, all full -> 1280 blocks = 5/CU exact
#define MT       64             // batch rows per block

// Fused prep+pos kernel block partition
#define PREP_BLOCKS (KPAD / 64)     // 160
#define POS_BLOCKS  (BATCH / 4)     // 1024

typedef __bf16 bf16_t;
typedef __bf16 bf16x8 __attribute__((ext_vector_type(8)));
typedef float  f32x4  __attribute__((ext_vector_type(4)));

// ---------------------------------------------------------------------------
// Kernel 1 (fused): blocks [0, PREP_BLOCKS) do the coalesced LDS-tiled
// transpose+convert user_emb[k][d] (f32) -> ueT[d][k] (bf16, k zero-padded);
// blocks [PREP_BLOCKS, PREP_BLOCKS+POS_BLOCKS) compute
//   out[b] = dot(user_emb[users[b]], item_emb[items[b]])
// with a plain store (initializes harness-poisoned d_out before atomics).
// Fusing removes one stream-serialized launch boundary and overlaps the two
// small independent phases.
// ---------------------------------------------------------------------------
__global__ __launch_bounds__(256) void prep_pos_kernel(
        const float* __restrict__ user_emb,
        const float* __restrict__ item_emb,
        const int* __restrict__ users,
        const int* __restrict__ items,
        bf16_t* __restrict__ ueT,
        float* __restrict__ out) {
    if (blockIdx.x < PREP_BLOCKS) {
        // ---- transpose tile ----
        __shared__ float tile[64][65];          // +1 pad: conflict-free
        const int t  = threadIdx.x;
        const int k0 = blockIdx.x * 64;
        const int x  = t & 63;
        const int r  = t >> 6;                  // 0..3
        #pragma unroll
        for (int i = 0; i < 16; ++i) {
            const int kl = i * 4 + r;
            const int k  = k0 + kl;
            tile[kl][x] = (k < NUSERS) ? user_emb[(size_t)k * DIM + x] : 0.0f;
        }
        __syncthreads();
        #pragma unroll
        for (int i = 0; i < 16; ++i) {
            const int dl = i * 4 + r;
            ueT[(size_t)dl * KPAD + k0 + x] = (bf16_t)tile[x][dl];
        }
    } else {
        // ---- positive dot: one wave per batch element ----
        const int w    = threadIdx.x >> 6;
        const int lane = threadIdx.x & 63;
        const int b    = (blockIdx.x - PREP_BLOCKS) * 4 + w;
        const int uid  = users[b];
        const int iid  = items[b];
        float v = user_emb[(size_t)uid * DIM + lane]
                * item_emb[(size_t)iid * DIM + lane];
        v += __shfl_xor(v, 32, 64);
        v += __shfl_xor(v, 16, 64);
        v += __shfl_xor(v, 8, 64);
        v += __shfl_xor(v, 4, 64);
        v += __shfl_xor(v, 2, 64);
        v += __shfl_xor(v, 1, 64);
        if (lane == 0) out[b] = v;
    }
}

// ---------------------------------------------------------------------------
// Kernel 2: social term — barrier-free, LDS-free, branchless, software-
// pipelined MFMA streaming GEMM.
//   V[m, d] = sum_k sw[users[m], k] * user_emb[k, d]
//   out[m] += sum_d V[m, d] * item_emb[items[m], d]
//
// Changes vs previous round:
//  * A loads are UNCONDITIONAL: k is clamped to NUSERS-8 (float4-aligned, and
//    the last-row read ends exactly at the buffer end). For clamped steps the
//    A values are garbage, but the matching B (ueT) rows are zero-padded
//    beyond k=10000, so those MFMA products contribute exactly 0.
//  * Explicit 1-step software pipeline: step s+1's 6 loads (2x float4 A,
//    4x bf16x8 B) are issued before step s's MFMAs, guaranteeing >=2 steps
//    (64 B/lane of A) in flight independent of compiler scheduling. With
//    ~16-20 waves/CU this gives 32-64 KB of A traffic in flight per CU,
//    well above the ~9 KB needed to sustain HBM BW at ~900-cycle latency.
//
// Grid: x = K-chunk (20, uniform 16 steps), y = M-tile (64). Block 256 =
// 4 waves; wave w owns rows [16w, 16w+16) x all 64 cols via four 16x16x32
// MFMA accumulators.
// ---------------------------------------------------------------------------
__global__ __launch_bounds__(256, 4) void social_kernel(
        const float* __restrict__ sw,
        const bf16_t* __restrict__ ueT,
        const float* __restrict__ item_emb,
        const int* __restrict__ users,
        const int* __restrict__ items,
        float* __restrict__ out) {
    const int tid  = threadIdx.x;
    const int lane = tid & 63;
    const int w    = tid >> 6;       // wave id: rows [16w, 16w+16)
    const int c    = lane & 15;      // A row within wave tile / B col in n-frag
    const int q    = lane >> 4;      // k sub-offset group 0..3

    const int m0    = blockIdx.y * MT;
    const int myrow = m0 + 16 * w + c;
    const size_t a_base = (size_t)users[myrow] * NUSERS;   // this lane's sw row

    // Per-lane B row bases (ueT[d][k], d = c + 16t)
    const bf16_t* b0p = ueT + (size_t)(c     ) * KPAD;
    const bf16_t* b1p = ueT + (size_t)(c + 16) * KPAD;
    const bf16_t* b2p = ueT + (size_t)(c + 32) * KPAD;
    const bf16_t* b3p = ueT + (size_t)(c + 48) * KPAD;

    f32x4 acc0 = {0.f, 0.f, 0.f, 0.f};
    f32x4 acc1 = {0.f, 0.f, 0.f, 0.f};
    f32x4 acc2 = {0.f, 0.f, 0.f, 0.f};
    f32x4 acc3 = {0.f, 0.f, 0.f, 0.f};

    const int kbase = blockIdx.x * (STEPS_PER_CHUNK * 32) + 8 * q;

    // ---- pipeline prologue: load step 0 ----
    {
        // first A offset never exceeds NUSERS-8 for s=0 of any chunk except
        // the clamp is still applied for uniformity
        int ka  = kbase;
        int kaA = (ka <= NUSERS - 8) ? ka : (NUSERS - 8);
        const float4* pa = (const float4*)(sw + a_base + kaA);
        // declared below via the rotating registers
        (void)pa;
    }
    int ka0  = kbase;
    int ka0A = (ka0 <= NUSERS - 8) ? ka0 : (NUSERS - 8);
    float4 a0 = *(const float4*)(sw + a_base + ka0A);
    float4 a1 = *(const float4*)(sw + a_base + ka0A + 4);
    bf16x8 b0 = *(const bf16x8*)(b0p + ka0);
    bf16x8 b1 = *(const bf16x8*)(b1p + ka0);
    bf16x8 b2 = *(const bf16x8*)(b2p + ka0);
    bf16x8 b3 = *(const bf16x8*)(b3p + ka0);

    #pragma unroll
    for (int s = 0; s < STEPS_PER_CHUNK; ++s) {
        float4 na0 = {0.f, 0.f, 0.f, 0.f};
        float4 na1 = {0.f, 0.f, 0.f, 0.f};
        bf16x8 nb0 = {}, nb1 = {}, nb2 = {}, nb3 = {};
        if (s + 1 < STEPS_PER_CHUNK) {     // static with full unroll
            const int kn  = kbase + 32 * (s + 1);
            const int knA = (kn <= NUSERS - 8) ? kn : (NUSERS - 8);
            na0 = *(const float4*)(sw + a_base + knA);
            na1 = *(const float4*)(sw + a_base + knA + 4);
            nb0 = *(const bf16x8*)(b0p + kn);
            nb1 = *(const bf16x8*)(b1p + kn);
            nb2 = *(const bf16x8*)(b2p + kn);
            nb3 = *(const bf16x8*)(b3p + kn);
        }

        bf16x8 av;
        av[0] = (bf16_t)a0.x; av[1] = (bf16_t)a0.y;
        av[2] = (bf16_t)a0.z; av[3] = (bf16_t)a0.w;
        av[4] = (bf16_t)a1.x; av[5] = (bf16_t)a1.y;
        av[6] = (bf16_t)a1.z; av[7] = (bf16_t)a1.w;

        acc0 = __builtin_amdgcn_mfma_f32_16x16x32_bf16(av, b0, acc0, 0, 0, 0);
        acc1 = __builtin_amdgcn_mfma_f32_16x16x32_bf16(av, b1, acc1, 0, 0, 0);
        acc2 = __builtin_amdgcn_mfma_f32_16x16x32_bf16(av, b2, acc2, 0, 0, 0);
        acc3 = __builtin_amdgcn_mfma_f32_16x16x32_bf16(av, b3, acc3, 0, 0, 0);

        a0 = na0; a1 = na1;
        b0 = nb0; b1 = nb1; b2 = nb2; b3 = nb3;
    }

    // Epilogue: C/D layout (verified m89): col = lane&15, row = (lane>>4)*4 + r.
    // Row (local) = 16w + 4q + r; col of acc_t element = 16t + c.
    // out_partial[row] = sum_d C[row][d] * item_emb[items[row]][d]
    #pragma unroll
    for (int r = 0; r < 4; ++r) {
        const int grow = m0 + 16 * w + 4 * q + r;
        const int iid  = items[grow];          // uniform across the 16-lane group
        const float* ie = item_emb + (size_t)iid * DIM;
        float v = acc0[r] * ie[c]
                + acc1[r] * ie[c + 16]
                + acc2[r] * ie[c + 32]
                + acc3[r] * ie[c + 48];
        // reduce across the 16 lanes (c = 0..15) holding this row
        v += __shfl_xor(v, 1, 64);
        v += __shfl_xor(v, 2, 64);
        v += __shfl_xor(v, 4, 64);
        v += __shfl_xor(v, 8, 64);
        if (c == 0) atomicAdd(out + grow, v);
    }
}

// ---------------------------------------------------------------------------
extern "C" void kernel_launch(void* const* d_in, const int* in_sizes, int n_in,
                              void* d_out, int out_size, void* d_ws, size_t ws_size,
                              hipStream_t stream) {
    const float* user_emb = (const float*)d_in[0];
    const float* item_emb = (const float*)d_in[1];
    const float* sw       = (const float*)d_in[2];
    const int*   users    = (const int*)d_in[3];
    const int*   items    = (const int*)d_in[4];
    float* out = (float*)d_out;

    bf16_t* ueT = (bf16_t*)d_ws;   // DIM * KPAD bf16 = 1.31 MB

    // 1) fused: transpose+convert user_emb  ||  positive dot (out init)
    prep_pos_kernel<<<PREP_BLOCKS + POS_BLOCKS, 256, 0, stream>>>(
        user_emb, item_emb, users, items, ueT, out);

    // 2) social GEMM + fused epilogue dot, atomic accumulate into out
    social_kernel<<<dim3(NCHUNK, BATCH / MT), 256, 0, stream>>>(
        sw, ueT, item_emb, users, items, out);
}